// Round 7
// baseline (2609.213 us; speedup 1.0000x reference)
//
#include <hip/hip_runtime.h>

#define B_   128
#define T_   128
#define DIN  64
#define H_   1024
#define NBLK 256
#define NTHR 512
#define NSLOT 5
#define DEPTH 4

typedef _Float16 f16;
typedef _Float16 half8 __attribute__((ext_vector_type(8)));
typedef float float4v __attribute__((ext_vector_type(4)));

// LDS layout:
//  W1s : f16[34][512]  lane-ordered fragments                34816 B
//  W2s : f16[64][512]                                        65536 B
//  RING: f16[8 waves][5 slots][512]                          40960 B
//  Sg1 : float[128][17]                                       8704 B
//  Sg2 : float[128][17]                                       8704 B
//  c1,c2: float[512] each                                     4096 B
//  bs1,bs2: float[16] each                                     128 B   total 162944
#define OFF_W2   34816
#define OFF_RING 100352
#define OFF_SG1  141312
#define OFF_SG2  150016
#define OFF_C1   158720
#define OFF_C2   160768
#define OFF_B1   162816
#define OFF_B2   162880
#define SMEM_BYTES 162944

// Barrier state S (unsigned[2048], 8 KB), one 128-B line per hot word:
//  S[x*32]         : per-XCD ticket
//  S[512]          : central XCD counter
//  S[544]          : release word            (polled by <=8 XCD leaders)
//  S[576 + x*32]   : per-XCD go flag         (polled by <=31 blocks)
//  S[1088 + x*32]  : per-XCD inv-done flag   (polled by 1 leader)
//  S[1600 + x]     : per-XCD block count     (preamble only)

struct Params {
  const float *x, *Wih1, *Whh1, *bih1, *bhh1, *Wih2, *Whh2, *bih2, *bhh2,
              *Wlin, *blin, *Whio, *bhio;
  const int* fut;
  float* out;
  f16 *x16, *h1a, *h1b, *h2a, *h2b, *ob;
  unsigned *arrive, *rel;
  unsigned *S;
};

__device__ __forceinline__ float sigm(float v) { return 1.f / (1.f + __expf(-v)); }
__device__ __forceinline__ float tanh_(float v) { return 2.f / (1.f + __expf(-2.f * v)) - 1.f; }

__device__ __forceinline__ unsigned get_xcc() {
  unsigned x;
  asm volatile("s_getreg_b32 %0, hwreg(HW_REG_XCC_ID)" : "=s"(x));
  return x & 15u;
}

__device__ __forceinline__ void stage_dma(const f16* src_lane, f16* lds_base) {
  __builtin_amdgcn_global_load_lds(
      (const __attribute__((address_space(1))) void*)src_lane,
      (__attribute__((address_space(3))) void*)lds_base, 16, 0, 0);
}

#define WAIT_VM(n)                                                        \
  do {                                                                    \
    switch (n) {                                                          \
      case 3: asm volatile("s_waitcnt vmcnt(3)" ::: "memory"); break;     \
      case 2: asm volatile("s_waitcnt vmcnt(2)" ::: "memory"); break;     \
      case 1: asm volatile("s_waitcnt vmcnt(1)" ::: "memory"); break;     \
      default: asm volatile("s_waitcnt vmcnt(0)" ::: "memory"); break;    \
    }                                                                     \
  } while (0)

// ---- slow barrier (preamble only) -----------------------------------------
__device__ __forceinline__ void grid_sync(unsigned* arrive, unsigned* rel, unsigned ph) {
  __syncthreads();
  const int tid = threadIdx.x, bid = blockIdx.x;
  if (bid == 0) {
    if (tid > 0 && tid < NBLK) {
      while (__hip_atomic_load(&arrive[tid], __ATOMIC_RELAXED, __HIP_MEMORY_SCOPE_AGENT) != ph)
        __builtin_amdgcn_s_sleep(8);
    }
    __syncthreads();
    if (tid == 0)
      __hip_atomic_store(rel, ph, __ATOMIC_RELEASE, __HIP_MEMORY_SCOPE_AGENT);
  } else {
    if (tid == 0) {
      __hip_atomic_store(&arrive[bid], ph, __ATOMIC_RELEASE, __HIP_MEMORY_SCOPE_AGENT);
      while (__hip_atomic_load(rel, __ATOMIC_RELAXED, __HIP_MEMORY_SCOPE_AGENT) != ph)
        __builtin_amdgcn_s_sleep(8);
    }
  }
  __syncthreads();
  __builtin_amdgcn_fence(__ATOMIC_ACQUIRE, "agent");
}

// ---- fast barrier v4: L2-inv hoisted to arrive-time (per-XCD last arriver,
// overlaps other XCDs' arrival skew). Post-release path: release -> inv-done
// (already set except straggler XCD) -> go flag -> L1-inv. Correct because
// h writes are write-through (never enter reader L2s) and stale lines are
// from >=2 phases back, so inv after MY XCD's last read suffices.
__device__ __forceinline__ void fast_sync(unsigned* S, unsigned x, unsigned xtotal,
                                          unsigned nxcd, unsigned ph) {
  __syncthreads();   // drains vmcnt: this block's write-through h stores done
  if (threadIdx.x == 0) {
    unsigned t = __hip_atomic_fetch_add(&S[x * 32], 1u, __ATOMIC_RELAXED, __HIP_MEMORY_SCOPE_AGENT);
    bool leader = (t % xtotal == 0u);
    if ((t + 1u) % xtotal == 0u) {            // last arriver of this XCD
      unsigned c = __hip_atomic_fetch_add(&S[512], 1u, __ATOMIC_RELAXED, __HIP_MEMORY_SCOPE_AGENT);
      if ((c + 1u) % nxcd == 0u)              // last XCD globally -> release
        __hip_atomic_store(&S[544], ph, __ATOMIC_RELAXED, __HIP_MEMORY_SCOPE_AGENT);
      asm volatile("buffer_inv sc0 sc1\n\ts_waitcnt vmcnt(0)" ::: "memory");
      __hip_atomic_store(&S[1088 + x * 32], ph, __ATOMIC_RELAXED, __HIP_MEMORY_SCOPE_AGENT);
    }
    if (leader) {
      while (__hip_atomic_load(&S[544], __ATOMIC_RELAXED, __HIP_MEMORY_SCOPE_AGENT) != ph)
        __builtin_amdgcn_s_sleep(1);
      while (__hip_atomic_load(&S[1088 + x * 32], __ATOMIC_RELAXED, __HIP_MEMORY_SCOPE_AGENT) != ph)
        __builtin_amdgcn_s_sleep(1);
      __hip_atomic_store(&S[576 + x * 32], ph, __ATOMIC_RELAXED, __HIP_MEMORY_SCOPE_AGENT);
      asm volatile("buffer_inv sc0\n\ts_waitcnt vmcnt(0)" ::: "memory");   // own L1, off-path
    } else {
      while (__hip_atomic_load(&S[576 + x * 32], __ATOMIC_RELAXED, __HIP_MEMORY_SCOPE_AGENT) != ph)
        __builtin_amdgcn_s_sleep(2);
      asm volatile("buffer_inv sc0\n\ts_waitcnt vmcnt(0)" ::: "memory");   // local L1
    }
  }
  __syncthreads();
}

__global__ void __launch_bounds__(NTHR, 1) lstm_k(Params p) {
  extern __shared__ char smem[];
  f16*   W1s  = (f16*)(smem);
  f16*   W2s  = (f16*)(smem + OFF_W2);
  f16*   RING = (f16*)(smem + OFF_RING);
  float* Sg1  = (float*)(smem + OFF_SG1);
  float* Sg2  = (float*)(smem + OFF_SG2);
  float* c1   = (float*)(smem + OFF_C1);
  float* c2   = (float*)(smem + OFF_C2);
  float* bs1  = (float*)(smem + OFF_B1);
  float* bs2  = (float*)(smem + OFF_B2);

  const int tid = threadIdx.x, bid = blockIdx.x;
  const int hb  = bid * 4;
  const int fut = p.fut[0];
  const unsigned xcc = get_xcc();
  unsigned* S = p.S;

  if (bid == 0) {
    for (int i = tid; i < 2048; i += NTHR)
      __hip_atomic_store(&S[i], 0u, __ATOMIC_RELAXED, __HIP_MEMORY_SCOPE_AGENT);
  }

  // ---------------- preamble ------------------------------------------------
  for (int idx = tid; idx < 34 * 512; idx += NTHR) {
    int c = idx >> 9, r = idx & 511;
    int q = r >> 7, colw = (r >> 3) & 15, j = r & 7;
    int k = c * 32 + q * 8 + j;
    int row = (colw >> 2) * H_ + hb + (colw & 3);
    float v = (k < H_) ? p.Whh1[row * H_ + k] : p.Wih1[row * DIN + (k - H_)];
    W1s[idx] = (f16)v;
  }
  for (int idx = tid; idx < 64 * 512; idx += NTHR) {
    int c = idx >> 9, r = idx & 511;
    int q = r >> 7, colw = (r >> 3) & 15, j = r & 7;
    int k = c * 32 + q * 8 + j;
    int row = (colw >> 2) * H_ + hb + (colw & 3);
    float v = (k < H_) ? p.Wih2[row * H_ + k] : p.Whh2[row * H_ + (k - H_)];
    W2s[idx] = (f16)v;
  }
  if (tid < 16) {
    int row = (tid >> 2) * H_ + hb + (tid & 3);
    bs1[tid] = p.bih1[row] + p.bhh1[row];
    bs2[tid] = p.bih2[row] + p.bhh2[row];
  }
  for (int i = tid; i < 512; i += NTHR) { c1[i] = 0.f; c2[i] = 0.f; }
  for (int i = bid * NTHR + tid; i < B_ * T_ * DIN; i += NBLK * NTHR)
    p.x16[i] = (f16)p.x[i];
  for (int i = bid * NTHR + tid; i < B_ * H_; i += NBLK * NTHR) {
    p.h1a[i] = (f16)0.f; p.h1b[i] = (f16)0.f;
    p.h2a[i] = (f16)0.f; p.h2b[i] = (f16)0.f;
  }

  unsigned ph = 1;
  grid_sync(p.arrive, p.rel, ph);
  if (tid == 0)
    __hip_atomic_fetch_add(&S[1600 + xcc], 1u, __ATOMIC_RELAXED, __HIP_MEMORY_SCOPE_AGENT);
  ++ph;
  grid_sync(p.arrive, p.rel, ph);

  unsigned xtotal = __hip_atomic_load(&S[1600 + xcc], __ATOMIC_RELAXED, __HIP_MEMORY_SCOPE_AGENT);
  unsigned nxcd = 0;
  for (int i = 0; i < 16; ++i)
    nxcd += (__hip_atomic_load(&S[1600 + i], __ATOMIC_RELAXED, __HIP_MEMORY_SCOPE_AGENT) != 0u);

  auto gsync = [&]() { ++ph; fast_sync(S, xcc, xtotal, nxcd, ph); };

  // ---------- wave geometry: 8 waves = 8 m-tiles (16 rows), full K ---------
  const int lane = tid & 63, wv = tid >> 6;
  const int col = lane & 15, quad = lane >> 4;
  const int m0 = wv * 16 + col;
  const int ko = quad * 8;
  const float b1v = bs1[col], b2v = bs2[col];
  const f16* W1f = W1s + lane * 8;
  const f16* W2f = W2s + lane * 8;
  f16* ringw = RING + wv * (NSLOT * 512);
  const int lane_off = (wv * 16 + col) * H_ + quad * 8;

  f16 *h1c = p.h1a, *h1n = p.h1b, *h2c = p.h2a, *h2n = p.h2b;

  auto lstm_pw = [&](const float* Sgb, float* cst, f16* hn) {
    int mm = tid >> 2, cc = tid & 3;
    float gi = Sgb[mm * 17 + cc],     gf = Sgb[mm * 17 + 4 + cc];
    float gg = Sgb[mm * 17 + 8 + cc], go = Sgb[mm * 17 + 12 + cc];
    float cn = sigm(gf) * cst[tid] + sigm(gi) * tanh_(gg);
    cst[tid] = cn;
    f16 hv = (f16)(sigm(go) * tanh_(cn));
    int v = (int)__builtin_bit_cast(unsigned short, hv);
    int base = lane & ~3;
    int v0 = __shfl(v, base, 64),     v1 = __shfl(v, base + 1, 64);
    int v2 = __shfl(v, base + 2, 64), v3 = __shfl(v, base + 3, 64);
    if (cc == 0) {
      unsigned long long pk = (unsigned long long)(unsigned short)v0
        | ((unsigned long long)(unsigned short)v1 << 16)
        | ((unsigned long long)(unsigned short)v2 << 32)
        | ((unsigned long long)(unsigned short)v3 << 48);
      __hip_atomic_store((unsigned long long*)(hn + mm * H_ + hb), pk,
                         __ATOMIC_RELAXED, __HIP_MEMORY_SCOPE_AGENT);
    }
  };

  auto phase = [&](bool l1, bool l2, const f16* xp, int xstr) {
    float4v a1 = {b1v, b1v, b1v, b1v};
    float4v a2 = {b2v, b2v, b2v, b2v};
    const int nwin = l2 ? 64 : 32;

    half8 ax0, ax1;
    if (l1) {
      ax0 = *(const half8*)(xp + m0 * xstr + ko);
      ax1 = *(const half8*)(xp + m0 * xstr + 32 + ko);
    }
    asm volatile("s_waitcnt vmcnt(0)" ::: "memory");

    {
      int slot = 0;
      for (int w = 0; w < DEPTH; ++w) {
        const f16* src = (w < 32) ? h1c : h2c;
        stage_dma(src + lane_off + (w & 31) * 32, ringw + slot * 512);
        if (++slot == NSLOT) slot = 0;
      }
    }
    if (l1) {
      a1 = __builtin_amdgcn_mfma_f32_16x16x32_f16(ax0, *(const half8*)(W1f + 32 * 512), a1, 0, 0, 0);
      a1 = __builtin_amdgcn_mfma_f32_16x16x32_f16(ax1, *(const half8*)(W1f + 33 * 512), a1, 0, 0, 0);
    }

    WAIT_VM(DEPTH - 1);
    half8 a_cur = *(const half8*)(ringw + lane * 8);
    int slot_i = DEPTH % NSLOT;
    int slot_n = 1;

    #pragma unroll 4
    for (int w = 0; w < nwin; ++w) {
      int wn = w + DEPTH;
      if (wn < nwin) {
        const f16* src = (wn < 32) ? h1c : h2c;
        stage_dma(src + lane_off + (wn & 31) * 32, ringw + slot_i * 512);
        if (++slot_i == NSLOT) slot_i = 0;
      }
      half8 a_next;
      if (w + 1 < nwin) {
        int rem = nwin - 2 - w;
        if (rem > DEPTH - 1) rem = DEPTH - 1;
        WAIT_VM(rem);
        a_next = *(const half8*)(ringw + slot_n * 512 + lane * 8);
        if (++slot_n == NSLOT) slot_n = 0;
      }
      if (l1 && w < 32)
        a1 = __builtin_amdgcn_mfma_f32_16x16x32_f16(a_cur, *(const half8*)(W1f + w * 512), a1, 0, 0, 0);
      if (l2)
        a2 = __builtin_amdgcn_mfma_f32_16x16x32_f16(a_cur, *(const half8*)(W2f + w * 512), a2, 0, 0, 0);
      a_cur = a_next;
    }
    asm volatile("s_waitcnt vmcnt(0)" ::: "memory");

    // ---- merged epilogue: one sync pair for both layers ----
    __syncthreads();
    if (l1) {
      #pragma unroll
      for (int r = 0; r < 4; ++r)
        Sg1[(wv * 16 + quad * 4 + r) * 17 + col] = a1[r];
    }
    if (l2) {
      #pragma unroll
      for (int r = 0; r < 4; ++r)
        Sg2[(wv * 16 + quad * 4 + r) * 17 + col] = a2[r];
    }
    __syncthreads();
    if (l1) lstm_pw(Sg1, c1, h1n);
    if (l2) lstm_pw(Sg2, c2, h2n);
  };

  auto out_phase = [&](const float* W, const float* bv, bool wout) {
    int j = bid & 63, mgp = bid >> 6;
    int rid = tid >> 4, ks = tid & 15;
    int mrow = mgp * 32 + rid;
    const f16* hr = h2c + mrow * H_ + ks * 64;
    const float* wr = W + j * H_ + ks * 64;
    float s = 0.f;
    #pragma unroll 8
    for (int k = 0; k < 64; ++k) s += (float)hr[k] * wr[k];
    s += __shfl_down(s, 8, 16);
    s += __shfl_down(s, 4, 16);
    s += __shfl_down(s, 2, 16);
    s += __shfl_down(s, 1, 16);
    if (ks == 0) {
      float v = s + bv[j];
      f16 hv = (f16)v;
      __hip_atomic_store((unsigned short*)&p.ob[mrow * 64 + j],
                         __builtin_bit_cast(unsigned short, hv),
                         __ATOMIC_RELAXED, __HIP_MEMORY_SCOPE_AGENT);
      if (wout) p.out[mrow * 64 + j] = v;
    }
  };

  // ---------------- time loop: 129 fused phases ----------------------------
  for (int t = -1; t < T_; ++t) {
    bool l1 = (t + 1 < T_), l2 = (t >= 0);
    phase(l1, l2, p.x16 + (t + 1) * DIN, T_ * DIN);
    gsync();
    if (l1) { f16* tm = h1c; h1c = h1n; h1n = tm; }
    if (l2) { f16* tm = h2c; h2c = h2n; h2n = tm; }
  }
  out_phase(p.Wlin, p.blin, fut == 0);
  gsync();
  for (int f = 0; f < fut; ++f) {
    phase(true, false, p.ob, 64);
    gsync();
    { f16* tm = h1c; h1c = h1n; h1n = tm; }
    phase(false, true, p.ob, 64);
    gsync();
    { f16* tm = h2c; h2c = h2n; h2n = tm; }
    out_phase(p.Whio, p.bhio, f == fut - 1);
    gsync();
  }
}

extern "C" void kernel_launch(void* const* d_in, const int* in_sizes, int n_in,
                              void* d_out, int out_size, void* d_ws, size_t ws_size,
                              hipStream_t stream) {
  char* w = (char*)d_ws;
  auto carve = [&](size_t n) { char* r = w; w += (n + 255) & ~(size_t)255; return r; };

  Params p;
  p.x    = (const float*)d_in[0];
  p.Wih1 = (const float*)d_in[1];
  p.Whh1 = (const float*)d_in[2];
  p.bih1 = (const float*)d_in[3];
  p.bhh1 = (const float*)d_in[4];
  p.Wih2 = (const float*)d_in[5];
  p.Whh2 = (const float*)d_in[6];
  p.bih2 = (const float*)d_in[7];
  p.bhh2 = (const float*)d_in[8];
  p.Wlin = (const float*)d_in[9];
  p.blin = (const float*)d_in[10];
  p.Whio = (const float*)d_in[11];
  p.bhio = (const float*)d_in[12];
  p.fut  = (const int*)d_in[13];
  p.out  = (float*)d_out;

  p.x16 = (f16*)carve((size_t)B_ * T_ * DIN * 2);
  p.h1a = (f16*)carve((size_t)B_ * H_ * 2);
  p.h1b = (f16*)carve((size_t)B_ * H_ * 2);
  p.h2a = (f16*)carve((size_t)B_ * H_ * 2);
  p.h2b = (f16*)carve((size_t)B_ * H_ * 2);
  p.ob  = (f16*)carve((size_t)B_ * 64 * 2);
  p.arrive = (unsigned*)carve(NBLK * sizeof(unsigned));
  p.rel    = (unsigned*)carve(256);
  p.S      = (unsigned*)carve(2048 * sizeof(unsigned));

  (void)hipFuncSetAttribute((const void*)lstm_k,
                            hipFuncAttributeMaxDynamicSharedMemorySize, SMEM_BYTES);
  void* args[] = { &p };
  (void)hipLaunchCooperativeKernel((void*)lstm_k, dim3(NBLK), dim3(NTHR),
                                   args, SMEM_BYTES, stream);
}

// Round 8
// 2579.781 us; speedup vs baseline: 1.0114x; 1.0114x over previous
//
#include <hip/hip_runtime.h>

#define B_   128
#define T_   128
#define DIN  64
#define H_   1024
#define NBLK 256
#define NTHR 512
#define NSLOT 9
#define DEPTH 8

typedef _Float16 f16;
typedef _Float16 half8 __attribute__((ext_vector_type(8)));
typedef float float4v __attribute__((ext_vector_type(4)));

// LDS layout:
//  W1s : f16[34][512]  lane-ordered fragments                34816 B
//  W2s : f16[32][512]  (Wih2 only; Whh2 lives in VGPRs)      32768 B
//  RING: f16[8 waves][9 slots][512]                          73728 B
//  Sg1 : float[128][17]                                       8704 B
//  Sg2 : float[128][17]                                       8704 B
//  c1,c2: float[512] each                                     4096 B
//  bs1,bs2: float[16] each                                     128 B   total 162944
#define OFF_W2   34816
#define OFF_RING 67584
#define OFF_SG1  141312
#define OFF_SG2  150016
#define OFF_C1   158720
#define OFF_C2   160768
#define OFF_B1   162816
#define OFF_B2   162880
#define SMEM_BYTES 162944

// Barrier state S (unsigned[2048], 8 KB), one 128-B line per hot word:
//  S[x*32]         : per-XCD ticket
//  S[512]          : central XCD counter
//  S[544]          : release word            (polled by <=8 XCD leaders)
//  S[576 + x*32]   : per-XCD go flag         (polled by <=31 blocks)
//  S[1088 + x*32]  : per-XCD inv-done flag   (polled by 1 leader)
//  S[1600 + x]     : per-XCD block count     (preamble only)

struct Params {
  const float *x, *Wih1, *Whh1, *bih1, *bhh1, *Wih2, *Whh2, *bih2, *bhh2,
              *Wlin, *blin, *Whio, *bhio;
  const int* fut;
  float* out;
  f16 *x16, *h1a, *h1b, *h2a, *h2b, *ob;
  unsigned *arrive, *rel;
  unsigned *S;
};

__device__ __forceinline__ float sigm(float v) { return 1.f / (1.f + __expf(-v)); }
__device__ __forceinline__ float tanh_(float v) { return 2.f / (1.f + __expf(-2.f * v)) - 1.f; }

__device__ __forceinline__ unsigned get_xcc() {
  unsigned x;
  asm volatile("s_getreg_b32 %0, hwreg(HW_REG_XCC_ID)" : "=s"(x));
  return x & 15u;
}

__device__ __forceinline__ void stage_dma(const f16* src_lane, f16* lds_base) {
  __builtin_amdgcn_global_load_lds(
      (const __attribute__((address_space(1))) void*)src_lane,
      (__attribute__((address_space(3))) void*)lds_base, 16, 0, 0);
}

#define WAIT_VM(n)                                                        \
  do {                                                                    \
    switch (n) {                                                          \
      case 8: asm volatile("s_waitcnt vmcnt(8)" ::: "memory"); break;     \
      case 7: asm volatile("s_waitcnt vmcnt(7)" ::: "memory"); break;     \
      case 6: asm volatile("s_waitcnt vmcnt(6)" ::: "memory"); break;     \
      case 5: asm volatile("s_waitcnt vmcnt(5)" ::: "memory"); break;     \
      case 4: asm volatile("s_waitcnt vmcnt(4)" ::: "memory"); break;     \
      case 3: asm volatile("s_waitcnt vmcnt(3)" ::: "memory"); break;     \
      case 2: asm volatile("s_waitcnt vmcnt(2)" ::: "memory"); break;     \
      case 1: asm volatile("s_waitcnt vmcnt(1)" ::: "memory"); break;     \
      default: asm volatile("s_waitcnt vmcnt(0)" ::: "memory"); break;    \
    }                                                                     \
  } while (0)

// ---- slow barrier (preamble only) -----------------------------------------
__device__ __forceinline__ void grid_sync(unsigned* arrive, unsigned* rel, unsigned ph) {
  __syncthreads();
  const int tid = threadIdx.x, bid = blockIdx.x;
  if (bid == 0) {
    if (tid > 0 && tid < NBLK) {
      while (__hip_atomic_load(&arrive[tid], __ATOMIC_RELAXED, __HIP_MEMORY_SCOPE_AGENT) != ph)
        __builtin_amdgcn_s_sleep(8);
    }
    __syncthreads();
    if (tid == 0)
      __hip_atomic_store(rel, ph, __ATOMIC_RELEASE, __HIP_MEMORY_SCOPE_AGENT);
  } else {
    if (tid == 0) {
      __hip_atomic_store(&arrive[bid], ph, __ATOMIC_RELEASE, __HIP_MEMORY_SCOPE_AGENT);
      while (__hip_atomic_load(rel, __ATOMIC_RELAXED, __HIP_MEMORY_SCOPE_AGENT) != ph)
        __builtin_amdgcn_s_sleep(8);
    }
  }
  __syncthreads();
  __builtin_amdgcn_fence(__ATOMIC_ACQUIRE, "agent");
}

// ---- fast barrier v4 (unchanged from R7): L2-inv at arrive-time -----------
__device__ __forceinline__ void fast_sync(unsigned* S, unsigned x, unsigned xtotal,
                                          unsigned nxcd, unsigned ph) {
  __syncthreads();
  if (threadIdx.x == 0) {
    unsigned t = __hip_atomic_fetch_add(&S[x * 32], 1u, __ATOMIC_RELAXED, __HIP_MEMORY_SCOPE_AGENT);
    bool leader = (t % xtotal == 0u);
    if ((t + 1u) % xtotal == 0u) {
      unsigned c = __hip_atomic_fetch_add(&S[512], 1u, __ATOMIC_RELAXED, __HIP_MEMORY_SCOPE_AGENT);
      if ((c + 1u) % nxcd == 0u)
        __hip_atomic_store(&S[544], ph, __ATOMIC_RELAXED, __HIP_MEMORY_SCOPE_AGENT);
      asm volatile("buffer_inv sc0 sc1\n\ts_waitcnt vmcnt(0)" ::: "memory");
      __hip_atomic_store(&S[1088 + x * 32], ph, __ATOMIC_RELAXED, __HIP_MEMORY_SCOPE_AGENT);
    }
    if (leader) {
      while (__hip_atomic_load(&S[544], __ATOMIC_RELAXED, __HIP_MEMORY_SCOPE_AGENT) != ph)
        __builtin_amdgcn_s_sleep(1);
      while (__hip_atomic_load(&S[1088 + x * 32], __ATOMIC_RELAXED, __HIP_MEMORY_SCOPE_AGENT) != ph)
        __builtin_amdgcn_s_sleep(1);
      __hip_atomic_store(&S[576 + x * 32], ph, __ATOMIC_RELAXED, __HIP_MEMORY_SCOPE_AGENT);
      asm volatile("buffer_inv sc0\n\ts_waitcnt vmcnt(0)" ::: "memory");
    } else {
      while (__hip_atomic_load(&S[576 + x * 32], __ATOMIC_RELAXED, __HIP_MEMORY_SCOPE_AGENT) != ph)
        __builtin_amdgcn_s_sleep(2);
      asm volatile("buffer_inv sc0\n\ts_waitcnt vmcnt(0)" ::: "memory");
    }
  }
  __syncthreads();
}

__global__ void __launch_bounds__(NTHR, 2) lstm_k(Params p) {
  extern __shared__ char smem[];
  f16*   W1s  = (f16*)(smem);
  f16*   W2s  = (f16*)(smem + OFF_W2);
  f16*   RING = (f16*)(smem + OFF_RING);
  float* Sg1  = (float*)(smem + OFF_SG1);
  float* Sg2  = (float*)(smem + OFF_SG2);
  float* c1   = (float*)(smem + OFF_C1);
  float* c2   = (float*)(smem + OFF_C2);
  float* bs1  = (float*)(smem + OFF_B1);
  float* bs2  = (float*)(smem + OFF_B2);

  const int tid = threadIdx.x, bid = blockIdx.x;
  const int hb  = bid * 4;
  const int fut = p.fut[0];
  const unsigned xcc = get_xcc();
  unsigned* S = p.S;

  // wave geometry (needed early for wreg load)
  const int lane = tid & 63, wv = tid >> 6;
  const int col = lane & 15, quad = lane >> 4;
  const int m0 = wv * 16 + col;
  const int ko = quad * 8;
  f16* ringw = RING + wv * (NSLOT * 512);
  const int lane_off = (wv * 16 + col) * H_ + quad * 8;

  if (bid == 0) {
    for (int i = tid; i < 2048; i += NTHR)
      __hip_atomic_store(&S[i], 0u, __ATOMIC_RELAXED, __HIP_MEMORY_SCOPE_AGENT);
  }

  // ---------------- preamble ------------------------------------------------
  for (int idx = tid; idx < 34 * 512; idx += NTHR) {
    int c = idx >> 9, r = idx & 511;
    int q = r >> 7, colw = (r >> 3) & 15, j = r & 7;
    int k = c * 32 + q * 8 + j;
    int row = (colw >> 2) * H_ + hb + (colw & 3);
    float v = (k < H_) ? p.Whh1[row * H_ + k] : p.Wih1[row * DIN + (k - H_)];
    W1s[idx] = (f16)v;
  }
  for (int idx = tid; idx < 32 * 512; idx += NTHR) {   // Wih2 only
    int c = idx >> 9, r = idx & 511;
    int q = r >> 7, colw = (r >> 3) & 15, j = r & 7;
    int k = c * 32 + q * 8 + j;
    int row = (colw >> 2) * H_ + hb + (colw & 3);
    W2s[idx] = (f16)p.Wih2[row * H_ + k];
  }
  // Whh2 -> per-lane registers (fragment layout, static indices)
  half8 wreg[32];
  {
    const int row2 = (col >> 2) * H_ + hb + (col & 3);
    const float* ws = p.Whh2 + row2 * H_ + ko;
    #pragma unroll
    for (int c = 0; c < 32; ++c) {
      float4v v0 = *(const float4v*)(ws + c * 32);
      float4v v1 = *(const float4v*)(ws + c * 32 + 4);
      half8 t;
      t[0] = (f16)v0[0]; t[1] = (f16)v0[1]; t[2] = (f16)v0[2]; t[3] = (f16)v0[3];
      t[4] = (f16)v1[0]; t[5] = (f16)v1[1]; t[6] = (f16)v1[2]; t[7] = (f16)v1[3];
      wreg[c] = t;
    }
  }
  if (tid < 16) {
    int row = (tid >> 2) * H_ + hb + (tid & 3);
    bs1[tid] = p.bih1[row] + p.bhh1[row];
    bs2[tid] = p.bih2[row] + p.bhh2[row];
  }
  for (int i = tid; i < 512; i += NTHR) { c1[i] = 0.f; c2[i] = 0.f; }
  for (int i = bid * NTHR + tid; i < B_ * T_ * DIN; i += NBLK * NTHR)
    p.x16[i] = (f16)p.x[i];
  for (int i = bid * NTHR + tid; i < B_ * H_; i += NBLK * NTHR) {
    p.h1a[i] = (f16)0.f; p.h1b[i] = (f16)0.f;
    p.h2a[i] = (f16)0.f; p.h2b[i] = (f16)0.f;
  }

  unsigned ph = 1;
  grid_sync(p.arrive, p.rel, ph);
  if (tid == 0)
    __hip_atomic_fetch_add(&S[1600 + xcc], 1u, __ATOMIC_RELAXED, __HIP_MEMORY_SCOPE_AGENT);
  ++ph;
  grid_sync(p.arrive, p.rel, ph);

  unsigned xtotal = __hip_atomic_load(&S[1600 + xcc], __ATOMIC_RELAXED, __HIP_MEMORY_SCOPE_AGENT);
  unsigned nxcd = 0;
  for (int i = 0; i < 16; ++i)
    nxcd += (__hip_atomic_load(&S[1600 + i], __ATOMIC_RELAXED, __HIP_MEMORY_SCOPE_AGENT) != 0u);

  auto gsync = [&]() { ++ph; fast_sync(S, xcc, xtotal, nxcd, ph); };

  const float b1v = bs1[col], b2v = bs2[col];
  const f16* W1f = W1s + lane * 8;
  const f16* W2f = W2s + lane * 8;

  f16 *h1c = p.h1a, *h1n = p.h1b, *h2c = p.h2a, *h2n = p.h2b;

  auto lstm_pw = [&](const float* Sgb, float* cst, f16* hn) {
    int mm = tid >> 2, cc = tid & 3;
    float gi = Sgb[mm * 17 + cc],     gf = Sgb[mm * 17 + 4 + cc];
    float gg = Sgb[mm * 17 + 8 + cc], go = Sgb[mm * 17 + 12 + cc];
    float cn = sigm(gf) * cst[tid] + sigm(gi) * tanh_(gg);
    cst[tid] = cn;
    f16 hv = (f16)(sigm(go) * tanh_(cn));
    int v = (int)__builtin_bit_cast(unsigned short, hv);
    int base = lane & ~3;
    int v0 = __shfl(v, base, 64),     v1 = __shfl(v, base + 1, 64);
    int v2 = __shfl(v, base + 2, 64), v3 = __shfl(v, base + 3, 64);
    if (cc == 0) {
      unsigned long long pk = (unsigned long long)(unsigned short)v0
        | ((unsigned long long)(unsigned short)v1 << 16)
        | ((unsigned long long)(unsigned short)v2 << 32)
        | ((unsigned long long)(unsigned short)v3 << 48);
      __hip_atomic_store((unsigned long long*)(hn + mm * H_ + hb), pk,
                         __ATOMIC_RELAXED, __HIP_MEMORY_SCOPE_AGENT);
    }
  };

  // fused phase. Window map: 0..1 = x (l1), 2..33 = h1, 34..65 = h2 (l2).
  auto phase = [&](bool l1, bool l2, const f16* xp, int xstr) {
    float4v a1 = {b1v, b1v, b1v, b1v};
    float4v a2 = {b2v, b2v, b2v, b2v};
    const int wstart = l1 ? 0 : 2;
    const int wend   = l2 ? 66 : 34;
    auto src_of = [&](int w) -> const f16* {
      if (w < 2)  return xp + m0 * xstr + w * 32 + ko;
      if (w < 34) return h1c + lane_off + (w - 2) * 32;
      return h2c + lane_off + (w - 34) * 32;
    };
    // preload DEPTH windows into slots 0..DEPTH-1
    #pragma unroll
    for (int i = 0; i < DEPTH; ++i)
      stage_dma(src_of(wstart + i), ringw + i * 512);
    int slot_i = DEPTH;        // NSLOT=9 > DEPTH=8
    int slot_c = 0;
    int w = wstart;

    // ---- X segment (windows 0..1, l1 only) ----
    if (l1) {
      #pragma unroll
      for (int i = 0; i < 2; ++i, ++w) {
        int wn = w + DEPTH;
        if (wn < wend) {
          stage_dma(src_of(wn), ringw + slot_i * 512);
          if (++slot_i == NSLOT) slot_i = 0;
        }
        int rem = wend - 1 - w; if (rem > DEPTH) rem = DEPTH;
        WAIT_VM(rem);
        half8 aw = *(const half8*)(ringw + slot_c * 512 + lane * 8);
        if (++slot_c == NSLOT) slot_c = 0;
        a1 = __builtin_amdgcn_mfma_f32_16x16x32_f16(aw, *(const half8*)(W1f + (32 + i) * 512), a1, 0, 0, 0);
      }
    }
    // ---- H1 segment (windows 2..33) ----
    #pragma unroll 4
    for (int i = 0; i < 32; ++i, ++w) {
      int wn = w + DEPTH;
      if (wn < wend) {
        stage_dma(src_of(wn), ringw + slot_i * 512);
        if (++slot_i == NSLOT) slot_i = 0;
      }
      int rem = wend - 1 - w; if (rem > DEPTH) rem = DEPTH;
      WAIT_VM(rem);
      half8 aw = *(const half8*)(ringw + slot_c * 512 + lane * 8);
      if (++slot_c == NSLOT) slot_c = 0;
      if (l1) a1 = __builtin_amdgcn_mfma_f32_16x16x32_f16(aw, *(const half8*)(W1f + i * 512), a1, 0, 0, 0);
      if (l2) a2 = __builtin_amdgcn_mfma_f32_16x16x32_f16(aw, *(const half8*)(W2f + i * 512), a2, 0, 0, 0);
    }
    // ---- H2 segment (windows 34..65, l2 only; register B-operands) ----
    if (l2) {
      #pragma unroll
      for (int c = 0; c < 32; ++c) {
        if (c < 24) {   // wn = 42+c < 66
          stage_dma(h2c + lane_off + (c + 8) * 32, ringw + slot_i * 512);
          if (++slot_i == NSLOT) slot_i = 0;
        }
        int rem = 31 - c; if (rem > DEPTH) rem = DEPTH;
        WAIT_VM(rem);
        half8 aw = *(const half8*)(ringw + slot_c * 512 + lane * 8);
        if (++slot_c == NSLOT) slot_c = 0;
        a2 = __builtin_amdgcn_mfma_f32_16x16x32_f16(aw, wreg[c], a2, 0, 0, 0);
      }
    }
    asm volatile("s_waitcnt vmcnt(0)" ::: "memory");

    // ---- merged epilogue ----
    __syncthreads();
    if (l1) {
      #pragma unroll
      for (int r = 0; r < 4; ++r)
        Sg1[(wv * 16 + quad * 4 + r) * 17 + col] = a1[r];
    }
    if (l2) {
      #pragma unroll
      for (int r = 0; r < 4; ++r)
        Sg2[(wv * 16 + quad * 4 + r) * 17 + col] = a2[r];
    }
    __syncthreads();
    if (l1) lstm_pw(Sg1, c1, h1n);
    if (l2) lstm_pw(Sg2, c2, h2n);
  };

  auto out_phase = [&](const float* W, const float* bv, bool wout) {
    int j = bid & 63, mgp = bid >> 6;
    int rid = tid >> 4, ks = tid & 15;
    int mrow = mgp * 32 + rid;
    const f16* hr = h2c + mrow * H_ + ks * 64;
    const float* wr = W + j * H_ + ks * 64;
    float s = 0.f;
    #pragma unroll 8
    for (int k = 0; k < 64; ++k) s += (float)hr[k] * wr[k];
    s += __shfl_down(s, 8, 16);
    s += __shfl_down(s, 4, 16);
    s += __shfl_down(s, 2, 16);
    s += __shfl_down(s, 1, 16);
    if (ks == 0) {
      float v = s + bv[j];
      f16 hv = (f16)v;
      __hip_atomic_store((unsigned short*)&p.ob[mrow * 64 + j],
                         __builtin_bit_cast(unsigned short, hv),
                         __ATOMIC_RELAXED, __HIP_MEMORY_SCOPE_AGENT);
      if (wout) p.out[mrow * 64 + j] = v;
    }
  };

  // ---------------- time loop: 129 fused phases ----------------------------
  for (int t = -1; t < T_; ++t) {
    bool l1 = (t + 1 < T_), l2 = (t >= 0);
    phase(l1, l2, p.x16 + (t + 1) * DIN, T_ * DIN);
    gsync();
    if (l1) { f16* tm = h1c; h1c = h1n; h1n = tm; }
    if (l2) { f16* tm = h2c; h2c = h2n; h2n = tm; }
  }
  out_phase(p.Wlin, p.blin, fut == 0);
  gsync();
  for (int f = 0; f < fut; ++f) {
    phase(true, false, p.ob, 64);
    gsync();
    { f16* tm = h1c; h1c = h1n; h1n = tm; }
    phase(false, true, p.ob, 64);
    gsync();
    { f16* tm = h2c; h2c = h2n; h2n = tm; }
    out_phase(p.Whio, p.bhio, f == fut - 1);
    gsync();
  }
}

extern "C" void kernel_launch(void* const* d_in, const int* in_sizes, int n_in,
                              void* d_out, int out_size, void* d_ws, size_t ws_size,
                              hipStream_t stream) {
  char* w = (char*)d_ws;
  auto carve = [&](size_t n) { char* r = w; w += (n + 255) & ~(size_t)255; return r; };

  Params p;
  p.x    = (const float*)d_in[0];
  p.Wih1 = (const float*)d_in[1];
  p.Whh1 = (const float*)d_in[2];
  p.bih1 = (const float*)d_in[3];
  p.bhh1 = (const float*)d_in[4];
  p.Wih2 = (const float*)d_in[5];
  p.Whh2 = (const float*)d_in[6];
  p.bih2 = (const float*)d_in[7];
  p.bhh2 = (const float*)d_in[8];
  p.Wlin = (const float*)d_in[9];
  p.blin = (const float*)d_in[10];
  p.Whio = (const float*)d_in[11];
  p.bhio = (const float*)d_in[12];
  p.fut  = (const int*)d_in[13];
  p.out  = (float*)d_out;

  p.x16 = (f16*)carve((size_t)B_ * T_ * DIN * 2);
  p.h1a = (f16*)carve((size_t)B_ * H_ * 2);
  p.h1b = (f16*)carve((size_t)B_ * H_ * 2);
  p.h2a = (f16*)carve((size_t)B_ * H_ * 2);
  p.h2b = (f16*)carve((size_t)B_ * H_ * 2);
  p.ob  = (f16*)carve((size_t)B_ * 64 * 2);
  p.arrive = (unsigned*)carve(NBLK * sizeof(unsigned));
  p.rel    = (unsigned*)carve(256);
  p.S      = (unsigned*)carve(2048 * sizeof(unsigned));

  (void)hipFuncSetAttribute((const void*)lstm_k,
                            hipFuncAttributeMaxDynamicSharedMemorySize, SMEM_BYTES);
  void* args[] = { &p };
  (void)hipLaunchCooperativeKernel((void*)lstm_k, dim3(NBLK), dim3(NTHR),
                                   args, SMEM_BYTES, stream);
}

// Round 10
// 1901.596 us; speedup vs baseline: 1.3721x; 1.3566x over previous
//
#include <hip/hip_runtime.h>

#define B_   128
#define T_   128
#define DIN  64
#define H_   1024
#define NBLK 256
#define NTHR 512

typedef _Float16 f16;
typedef _Float16 half8 __attribute__((ext_vector_type(8)));
typedef float float4v __attribute__((ext_vector_type(4)));
typedef unsigned uint2v __attribute__((ext_vector_type(2)));
typedef unsigned uint4v __attribute__((ext_vector_type(4)));

// h layout (block-major, exclusive line ownership):
//   h(m, col) at  buf[(col>>2)*512 + m*4 + (col&3)]   (f16 elements)
// Block b writes its 4 columns as ONE contiguous 1KB region [b*512 .. b*512+512).
// No cache line is written by more than one block -> no partial-line RMW.

// LDS layout:
//  W1s : f16[34][512]  lane-ordered fragments                34816 B
//  W2s : f16[64][512]  (0..31 Wih2 vs h1, 32..63 Whh2 vs h2) 65536 B
//  Sg1 : float[128][17]                                       8704 B
//  Sg2 : float[128][17]                                       8704 B
//  c1,c2: float[512] each                                     4096 B
//  bs1,bs2: float[16] each                                     128 B   total 121984
#define OFF_W2   34816
#define OFF_SG1  100352
#define OFF_SG2  109056
#define OFF_C1   117760
#define OFF_C2   119808
#define OFF_B1   121856
#define OFF_B2   121920
#define SMEM_BYTES 121984

// Barrier state S (unsigned[2048], 8 KB), one 128-B line per hot word:
//  S[x*32]         : per-XCD ticket
//  S[512]          : central XCD counter
//  S[544]          : release word            (polled by <=8 XCD leaders)
//  S[576 + x*32]   : per-XCD go flag         (polled by <=31 blocks)
//  S[1088 + x*32]  : per-XCD inv-done flag   (polled by 1 leader)
//  S[1600 + x]     : per-XCD block count     (preamble only)

struct Params {
  const float *x, *Wih1, *Whh1, *bih1, *bhh1, *Wih2, *Whh2, *bih2, *bhh2,
              *Wlin, *blin, *Whio, *bhio;
  const int* fut;
  float* out;
  f16 *x16, *h1a, *h1b, *h2a, *h2b, *ob;
  unsigned *arrive, *rel;
  unsigned *S;
};

__device__ __forceinline__ float sigm(float v) { return 1.f / (1.f + __expf(-v)); }
__device__ __forceinline__ float tanh_(float v) { return 2.f / (1.f + __expf(-2.f * v)) - 1.f; }

__device__ __forceinline__ unsigned get_xcc() {
  unsigned x;
  asm volatile("s_getreg_b32 %0, hwreg(HW_REG_XCC_ID)" : "=s"(x));
  return x & 15u;
}

// ---- slow barrier (preamble only) -----------------------------------------
__device__ __forceinline__ void grid_sync(unsigned* arrive, unsigned* rel, unsigned ph) {
  __syncthreads();
  const int tid = threadIdx.x, bid = blockIdx.x;
  if (bid == 0) {
    if (tid > 0 && tid < NBLK) {
      while (__hip_atomic_load(&arrive[tid], __ATOMIC_RELAXED, __HIP_MEMORY_SCOPE_AGENT) != ph)
        __builtin_amdgcn_s_sleep(8);
    }
    __syncthreads();
    if (tid == 0)
      __hip_atomic_store(rel, ph, __ATOMIC_RELEASE, __HIP_MEMORY_SCOPE_AGENT);
  } else {
    if (tid == 0) {
      __hip_atomic_store(&arrive[bid], ph, __ATOMIC_RELEASE, __HIP_MEMORY_SCOPE_AGENT);
      while (__hip_atomic_load(rel, __ATOMIC_RELAXED, __HIP_MEMORY_SCOPE_AGENT) != ph)
        __builtin_amdgcn_s_sleep(8);
    }
  }
  __syncthreads();
  __builtin_amdgcn_fence(__ATOMIC_ACQUIRE, "agent");
}

// ---- fast barrier v4 (R8-proven): L2-inv hoisted to arrive-time -----------
__device__ __forceinline__ void fast_sync(unsigned* S, unsigned x, unsigned xtotal,
                                          unsigned nxcd, unsigned ph) {
  __syncthreads();
  if (threadIdx.x == 0) {
    unsigned t = __hip_atomic_fetch_add(&S[x * 32], 1u, __ATOMIC_RELAXED, __HIP_MEMORY_SCOPE_AGENT);
    bool leader = (t % xtotal == 0u);
    if ((t + 1u) % xtotal == 0u) {
      unsigned c = __hip_atomic_fetch_add(&S[512], 1u, __ATOMIC_RELAXED, __HIP_MEMORY_SCOPE_AGENT);
      if ((c + 1u) % nxcd == 0u)
        __hip_atomic_store(&S[544], ph, __ATOMIC_RELAXED, __HIP_MEMORY_SCOPE_AGENT);
      asm volatile("buffer_inv sc0 sc1\n\ts_waitcnt vmcnt(0)" ::: "memory");
      __hip_atomic_store(&S[1088 + x * 32], ph, __ATOMIC_RELAXED, __HIP_MEMORY_SCOPE_AGENT);
    }
    if (leader) {
      while (__hip_atomic_load(&S[544], __ATOMIC_RELAXED, __HIP_MEMORY_SCOPE_AGENT) != ph)
        __builtin_amdgcn_s_sleep(1);
      while (__hip_atomic_load(&S[1088 + x * 32], __ATOMIC_RELAXED, __HIP_MEMORY_SCOPE_AGENT) != ph)
        __builtin_amdgcn_s_sleep(1);
      __hip_atomic_store(&S[576 + x * 32], ph, __ATOMIC_RELAXED, __HIP_MEMORY_SCOPE_AGENT);
      asm volatile("buffer_inv sc0\n\ts_waitcnt vmcnt(0)" ::: "memory");
    } else {
      while (__hip_atomic_load(&S[576 + x * 32], __ATOMIC_RELAXED, __HIP_MEMORY_SCOPE_AGENT) != ph)
        __builtin_amdgcn_s_sleep(2);
      asm volatile("buffer_inv sc0\n\ts_waitcnt vmcnt(0)" ::: "memory");
    }
  }
  __syncthreads();
}

__global__ void __launch_bounds__(NTHR, 1) lstm_k(Params p) {
  extern __shared__ char smem[];
  f16*   W1s  = (f16*)(smem);
  f16*   W2s  = (f16*)(smem + OFF_W2);
  float* Sg1  = (float*)(smem + OFF_SG1);
  float* Sg2  = (float*)(smem + OFF_SG2);
  float* c1   = (float*)(smem + OFF_C1);
  float* c2   = (float*)(smem + OFF_C2);
  float* bs1  = (float*)(smem + OFF_B1);
  float* bs2  = (float*)(smem + OFF_B2);

  const int tid = threadIdx.x, bid = blockIdx.x;
  const int hb  = bid * 4;
  const int fut = p.fut[0];
  const unsigned xcc = get_xcc();
  unsigned* S = p.S;

  if (bid == 0) {
    for (int i = tid; i < 2048; i += NTHR)
      __hip_atomic_store(&S[i], 0u, __ATOMIC_RELAXED, __HIP_MEMORY_SCOPE_AGENT);
  }

  // ---------------- preamble ------------------------------------------------
  for (int idx = tid; idx < 34 * 512; idx += NTHR) {
    int c = idx >> 9, r = idx & 511;
    int q = r >> 7, colw = (r >> 3) & 15, j = r & 7;
    int k = c * 32 + q * 8 + j;
    int row = (colw >> 2) * H_ + hb + (colw & 3);
    float v = (k < H_) ? p.Whh1[row * H_ + k] : p.Wih1[row * DIN + (k - H_)];
    W1s[idx] = (f16)v;
  }
  for (int idx = tid; idx < 64 * 512; idx += NTHR) {
    int c = idx >> 9, r = idx & 511;
    int q = r >> 7, colw = (r >> 3) & 15, j = r & 7;
    int k = c * 32 + q * 8 + j;
    int row = (colw >> 2) * H_ + hb + (colw & 3);
    float v = (k < H_) ? p.Wih2[row * H_ + k] : p.Whh2[row * H_ + (k - H_)];
    W2s[idx] = (f16)v;
  }
  if (tid < 16) {
    int row = (tid >> 2) * H_ + hb + (tid & 3);
    bs1[tid] = p.bih1[row] + p.bhh1[row];
    bs2[tid] = p.bih2[row] + p.bhh2[row];
  }
  for (int i = tid; i < 512; i += NTHR) { c1[i] = 0.f; c2[i] = 0.f; }
  for (int i = bid * NTHR + tid; i < B_ * T_ * DIN; i += NBLK * NTHR)
    p.x16[i] = (f16)p.x[i];
  for (int i = bid * NTHR + tid; i < B_ * H_; i += NBLK * NTHR) {
    p.h1a[i] = (f16)0.f; p.h1b[i] = (f16)0.f;
    p.h2a[i] = (f16)0.f; p.h2b[i] = (f16)0.f;
  }

  unsigned ph = 1;
  grid_sync(p.arrive, p.rel, ph);
  if (tid == 0)
    __hip_atomic_fetch_add(&S[1600 + xcc], 1u, __ATOMIC_RELAXED, __HIP_MEMORY_SCOPE_AGENT);
  ++ph;
  grid_sync(p.arrive, p.rel, ph);

  unsigned xtotal = __hip_atomic_load(&S[1600 + xcc], __ATOMIC_RELAXED, __HIP_MEMORY_SCOPE_AGENT);
  unsigned nxcd = 0;
  for (int i = 0; i < 16; ++i)
    nxcd += (__hip_atomic_load(&S[1600 + i], __ATOMIC_RELAXED, __HIP_MEMORY_SCOPE_AGENT) != 0u);

  auto gsync = [&]() { ++ph; fast_sync(S, xcc, xtotal, nxcd, ph); };

  // ---------- wave geometry: 8 waves = 8 m-tiles (16 rows), full K ---------
  const int lane = tid & 63, wv = tid >> 6;
  const int col = lane & 15, quad = lane >> 4;
  const int m0 = wv * 16 + col;
  const int ko = quad * 8;
  const float b1v = bs1[col], b2v = bs2[col];
  const f16* W1f = W1s + lane * 8;
  const f16* W2f = W2s + lane * 8;
  // block-major h read base: window j pieces at hX + j*4096 + hoff and +512
  const int hoff = quad * 1024 + m0 * 4;

  f16 *h1c = p.h1a, *h1n = p.h1b, *h2c = p.h2a, *h2n = p.h2b;

  auto lstm_pw = [&](const float* Sgb, float* cst, f16* hn) {
    int mm = tid >> 2, cc = tid & 3;
    float gi = Sgb[mm * 17 + cc],     gf = Sgb[mm * 17 + 4 + cc];
    float gg = Sgb[mm * 17 + 8 + cc], go = Sgb[mm * 17 + 12 + cc];
    float cn = sigm(gf) * cst[tid] + sigm(gi) * tanh_(gg);
    cst[tid] = cn;
    f16 hv = (f16)(sigm(go) * tanh_(cn));
    int v = (int)__builtin_bit_cast(unsigned short, hv);
    int base = lane & ~3;
    int v0 = __shfl(v, base, 64),     v1 = __shfl(v, base + 1, 64);
    int v2 = __shfl(v, base + 2, 64), v3 = __shfl(v, base + 3, 64);
    if (cc == 0) {
      unsigned long long pk = (unsigned long long)(unsigned short)v0
        | ((unsigned long long)(unsigned short)v1 << 16)
        | ((unsigned long long)(unsigned short)v2 << 32)
        | ((unsigned long long)(unsigned short)v3 << 48);
      // block-major: this block's exclusive 1KB region, contiguous
      __hip_atomic_store((unsigned long long*)(hn + bid * 512 + mm * 4), pk,
                         __ATOMIC_RELAXED, __HIP_MEMORY_SCOPE_AGENT);
    }
  };

  auto ldwin = [&](const f16* hX, int j) -> half8 {
    const uint2v* q0 = (const uint2v*)(hX + j * 4096 + hoff);
    const uint2v* q1 = (const uint2v*)(hX + j * 4096 + hoff + 512);
    uint2v u0 = *q0, u1 = *q1;
    uint4v u = {u0[0], u0[1], u1[0], u1[1]};
    return __builtin_bit_cast(half8, u);
  };

  // fused phase: gates1(t+1) [l1] and gates2(t) [l2], both keyed on h1c
  auto phase = [&](bool l1, bool l2, const f16* xp, int xstr) {
    float4v a1 = {b1v, b1v, b1v, b1v};
    float4v a2 = {b2v, b2v, b2v, b2v};

    if (l1) {   // x part (row-major, read-only, cached)
      half8 ax0 = *(const half8*)(xp + m0 * xstr + ko);
      half8 ax1 = *(const half8*)(xp + m0 * xstr + 32 + ko);
      a1 = __builtin_amdgcn_mfma_f32_16x16x32_f16(ax0, *(const half8*)(W1f + 32 * 512), a1, 0, 0, 0);
      a1 = __builtin_amdgcn_mfma_f32_16x16x32_f16(ax1, *(const half8*)(W1f + 33 * 512), a1, 0, 0, 0);
    }
    if (l1 && l2) {
      #pragma unroll 4
      for (int j = 0; j < 32; ++j) {
        half8 aw = ldwin(h1c, j);
        a1 = __builtin_amdgcn_mfma_f32_16x16x32_f16(aw, *(const half8*)(W1f + j * 512), a1, 0, 0, 0);
        a2 = __builtin_amdgcn_mfma_f32_16x16x32_f16(aw, *(const half8*)(W2f + j * 512), a2, 0, 0, 0);
      }
    } else if (l1) {
      #pragma unroll 4
      for (int j = 0; j < 32; ++j) {
        half8 aw = ldwin(h1c, j);
        a1 = __builtin_amdgcn_mfma_f32_16x16x32_f16(aw, *(const half8*)(W1f + j * 512), a1, 0, 0, 0);
      }
    } else {
      #pragma unroll 4
      for (int j = 0; j < 32; ++j) {
        half8 aw = ldwin(h1c, j);
        a2 = __builtin_amdgcn_mfma_f32_16x16x32_f16(aw, *(const half8*)(W2f + j * 512), a2, 0, 0, 0);
      }
    }
    if (l2) {
      #pragma unroll 4
      for (int j = 0; j < 32; ++j) {
        half8 aw = ldwin(h2c, j);
        a2 = __builtin_amdgcn_mfma_f32_16x16x32_f16(aw, *(const half8*)(W2f + (32 + j) * 512), a2, 0, 0, 0);
      }
    }

    // ---- merged epilogue ----
    __syncthreads();
    if (l1) {
      #pragma unroll
      for (int r = 0; r < 4; ++r)
        Sg1[(wv * 16 + quad * 4 + r) * 17 + col] = a1[r];
    }
    if (l2) {
      #pragma unroll
      for (int r = 0; r < 4; ++r)
        Sg2[(wv * 16 + quad * 4 + r) * 17 + col] = a2[r];
    }
    __syncthreads();
    if (l1) lstm_pw(Sg1, c1, h1n);
    if (l2) lstm_pw(Sg2, c2, h2n);
  };

  // small projection: out[m][j] = h2 . W[j] + b[j]  (block-major h2 reads)
  auto out_phase = [&](const float* W, const float* bv, bool wout) {
    int j = bid & 63, mgp = bid >> 6;
    int rid = tid >> 4, ks = tid & 15;
    int mrow = mgp * 32 + rid;
    const float* wr = W + j * H_ + ks * 64;
    float s = 0.f;
    #pragma unroll
    for (int q = 0; q < 16; ++q) {
      // k-chunk = ks*64 + q*4 -> block (ks*16+q), cols 0..3, row mrow
      const uint2v* hp = (const uint2v*)(h2c + (ks * 16 + q) * 512 + mrow * 4);
      uint2v u = *hp;
      half8 hv4;
      { uint4v t = {u[0], u[1], 0u, 0u}; hv4 = __builtin_bit_cast(half8, t); }
      s += (float)hv4[0] * wr[q * 4 + 0] + (float)hv4[1] * wr[q * 4 + 1]
         + (float)hv4[2] * wr[q * 4 + 2] + (float)hv4[3] * wr[q * 4 + 3];
    }
    s += __shfl_down(s, 8, 16);
    s += __shfl_down(s, 4, 16);
    s += __shfl_down(s, 2, 16);
    s += __shfl_down(s, 1, 16);
    if (ks == 0) {
      float v = s + bv[j];
      f16 hv = (f16)v;
      __hip_atomic_store((unsigned short*)&p.ob[mrow * 64 + j],
                         __builtin_bit_cast(unsigned short, hv),
                         __ATOMIC_RELAXED, __HIP_MEMORY_SCOPE_AGENT);
      if (wout) p.out[mrow * 64 + j] = v;
    }
  };

  // ---------------- time loop: 129 fused phases ----------------------------
  for (int t = -1; t < T_; ++t) {
    bool l1 = (t + 1 < T_), l2 = (t >= 0);
    phase(l1, l2, p.x16 + (t + 1) * DIN, T_ * DIN);
    gsync();
    if (l1) { f16* tm = h1c; h1c = h1n; h1n = tm; }
    if (l2) { f16* tm = h2c; h2c = h2n; h2n = tm; }
  }
  out_phase(p.Wlin, p.blin, fut == 0);
  gsync();
  for (int f = 0; f < fut; ++f) {
    phase(true, false, p.ob, 64);
    gsync();
    { f16* tm = h1c; h1c = h1n; h1n = tm; }
    phase(false, true, p.ob, 64);
    gsync();
    { f16* tm = h2c; h2c = h2n; h2n = tm; }
    out_phase(p.Whio, p.bhio, f == fut - 1);
    gsync();
  }
}

extern "C" void kernel_launch(void* const* d_in, const int* in_sizes, int n_in,
                              void* d_out, int out_size, void* d_ws, size_t ws_size,
                              hipStream_t stream) {
  char* w = (char*)d_ws;
  auto carve = [&](size_t n) { char* r = w; w += (n + 255) & ~(size_t)255; return r; };

  Params p;
  p.x    = (const float*)d_in[0];
  p.Wih1 = (const float*)d_in[1];
  p.Whh1 = (const float*)d_in[2];
  p.bih1 = (const float*)d_in[3];
  p.bhh1 = (const float*)d_in[4];
  p.Wih2 = (const float*)d_in[5];
  p.Whh2 = (const float*)d_in[6];
  p.bih2 = (const float*)d_in[7];
  p.bhh2 = (const float*)d_in[8];
  p.Wlin = (const float*)d_in[9];
  p.blin = (const float*)d_in[10];
  p.Whio = (const float*)d_in[11];
  p.bhio = (const float*)d_in[12];
  p.fut  = (const int*)d_in[13];
  p.out  = (float*)d_out;

  p.x16 = (f16*)carve((size_t)B_ * T_ * DIN * 2);
  p.h1a = (f16*)carve((size_t)B_ * H_ * 2);
  p.h1b = (f16*)carve((size_t)B_ * H_ * 2);
  p.h2a = (f16*)carve((size_t)B_ * H_ * 2);
  p.h2b = (f16*)carve((size_t)B_ * H_ * 2);
  p.ob  = (f16*)carve((size_t)B_ * 64 * 2);
  p.arrive = (unsigned*)carve(NBLK * sizeof(unsigned));
  p.rel    = (unsigned*)carve(256);
  p.S      = (unsigned*)carve(2048 * sizeof(unsigned));

  (void)hipFuncSetAttribute((const void*)lstm_k,
                            hipFuncAttributeMaxDynamicSharedMemorySize, SMEM_BYTES);
  void* args[] = { &p };
  (void)hipLaunchCooperativeKernel((void*)lstm_k, dim3(NBLK), dim3(NTHR),
                                   args, SMEM_BYTES, stream);
}